// Round 7
// baseline (77.719 us; speedup 1.0000x reference)
//
#include <hip/hip_runtime.h>
#include <hip/hip_bf16.h>
#include <cstdint>

#define N 4096
#define CC 256
#define CH 32
#define L2E 1.4426950408889634f

typedef __attribute__((ext_vector_type(8)))  short short8;
typedef __attribute__((ext_vector_type(16))) float f32x16;
typedef __attribute__((ext_vector_type(4)))  uint32_t u32x4;

// ---- workspace float offsets ----
#define OFF_WFRAG 0            // wfragb [6][16 kb][64 lane][8 j] bf16 (as u16)
#define OFF_WOT   49152        // wot   [2][512][256] fp32
#define OFF_WEFF  311296       // weff  [2][64][256] fp32
#define OFF_BEFF  344064       // beff  [2][256] fp32
#define OFF_QF    344576       // Qf [2][2][128 nt][2 half][64 lane][8] bf16 (scaled by log2e)
#define OFF_KF    606720       // Kf [2][2][128 nt][2 half][64 lane][8] bf16
#define OFF_VF    868864       // Vf [2][2][128 nt][2 fr  ][64 lane][8] bf16
#define OFF_AOT   1131008      // aot [8][32][4096] fp32   (ib = (ia*2+ik)*2+b)

__device__ __forceinline__ uint32_t cvtpk_bf16(float lo, float hi) {
  uint32_t r;
  asm("v_cvt_pk_bf16_f32 %0, %1, %2" : "=v"(r) : "v"(lo), "v"(hi));
  return r;
}

// D-layout rows (16 regs, row=(r&3)+8*(r>>2)+4*l5, col=l31) -> two bf16 frags
// (lane l31 = col, slots l5*8+j = rows 0..15 / 16..31). Verbatim from validated attn.
__device__ __forceinline__ void rows_to_frags(const float* p, u32x4& lo, u32x4& hi) {
#pragma unroll
  for (int kh = 0; kh < 2; ++kh) {
    int base = kh * 8;
    uint32_t x0 = cvtpk_bf16(p[base + 0], p[base + 1]);
    uint32_t y0 = cvtpk_bf16(p[base + 4], p[base + 5]);
    asm volatile("v_permlane32_swap_b32 %0, %1" : "+v"(x0), "+v"(y0));
    uint32_t x1 = cvtpk_bf16(p[base + 2], p[base + 3]);
    uint32_t y1 = cvtpk_bf16(p[base + 6], p[base + 7]);
    asm volatile("v_permlane32_swap_b32 %0, %1" : "+v"(x1), "+v"(y1));
    u32x4 r; r[0] = x0; r[1] = x1; r[2] = y0; r[3] = y1;
    if (kh == 0) lo = r; else hi = r;
  }
}

// ------------------------------------------------------------------
// 1) prep: weight MFMA-frag table (bf16) + transposed wo (fp32)
//    wfragb elem (q, kb, lane, j) = w_q[ch = lane&31][c = kb*16 + (lane>>5)*8 + j]
// ------------------------------------------------------------------
__global__ void k_prep(const float* __restrict__ wf1, const float* __restrict__ wg1,
                       const float* __restrict__ wh1, const float* __restrict__ wf2,
                       const float* __restrict__ wg2, const float* __restrict__ wh2,
                       const float* __restrict__ wo1, const float* __restrict__ wo2,
                       uint16_t* __restrict__ wfragb, float* __restrict__ wot) {
  int bid = blockIdx.x;
  if (bid < 192) {
    int idx = bid * 256 + threadIdx.x;                 // < 49152 u16
    int q = idx >> 13, kb = (idx >> 9) & 15, l = (idx >> 3) & 63, j = idx & 7;
    int ch = l & 31, c = kb * 16 + (l >> 5) * 8 + j;
    const float* w = q == 0 ? wf1 : q == 1 ? wg1 : q == 2 ? wh1
                   : q == 3 ? wf2 : q == 4 ? wg2 : wh2;
    wfragb[idx] = (uint16_t)cvtpk_bf16(w[ch * CC + c], 0.f);
  } else {
    int idx = (bid - 192) * 256 + threadIdx.x;         // < 262144
    int o = idx & 255, j = (idx >> 8) & 511, r = idx >> 17;
    const float* wo = r == 0 ? wo1 : wo2;
    wot[idx] = wo[o * 512 + j];
  }
}

// ------------------------------------------------------------------
// 2) effective epilogue weights: Weff = wo * [wv_a; wv_b], beff = bo + wo*bv
//    [r7] 8-way independent accumulators break the serial load->fma chain
//    (was latency-bound: 256 x ~250cy at 2 waves/CU ~= 27 us).
// ------------------------------------------------------------------
__global__ void k_weff(const float* __restrict__ wot,
                       const float* __restrict__ wv11, const float* __restrict__ wv12,
                       const float* __restrict__ wv21, const float* __restrict__ wv22,
                       const float* __restrict__ bv11, const float* __restrict__ bv12,
                       const float* __restrict__ bv21, const float* __restrict__ bv22,
                       const float* __restrict__ bo1, const float* __restrict__ bo2,
                       float* __restrict__ weff, float* __restrict__ beff) {
  int bid = blockIdx.x;
  int o = threadIdx.x;
  if (bid < 128) {
    int r = bid >> 6, ch = bid & 63, half = ch >> 5, chp = ch & 31;
    const float* wv = (r == 0) ? (half ? wv12 : wv11) : (half ? wv22 : wv21);
    const float* wocol = wot + ((size_t)r * 512 + half * 256) * 256 + o;
    float a[8];
#pragma unroll
    for (int u = 0; u < 8; ++u) a[u] = 0.f;
#pragma unroll 4
    for (int c = 0; c < 256; c += 8) {
#pragma unroll
      for (int u = 0; u < 8; ++u)
        a[u] = fmaf(wocol[(size_t)(c + u) * 256], wv[(c + u) * CH + chp], a[u]);
    }
    weff[((size_t)r * 64 + ch) * 256 + o] =
        ((a[0] + a[1]) + (a[2] + a[3])) + ((a[4] + a[5]) + (a[6] + a[7]));
  } else {
    int r = bid - 128;
    const float* bo  = r == 0 ? bo1 : bo2;
    const float* bva = r == 0 ? bv11 : bv21;
    const float* bvb = r == 0 ? bv12 : bv22;
    const float* wocol = wot + (size_t)r * 512 * 256 + o;
    float a[4], b4[4];
#pragma unroll
    for (int u = 0; u < 4; ++u) { a[u] = 0.f; b4[u] = 0.f; }
#pragma unroll 8
    for (int c = 0; c < 256; c += 4) {
#pragma unroll
      for (int u = 0; u < 4; ++u) {
        a[u]  = fmaf(wocol[(size_t)(c + u) * 256],       bva[c + u], a[u]);
        b4[u] = fmaf(wocol[(size_t)(c + u + 256) * 256], bvb[c + u], b4[u]);
      }
    }
    beff[r * 256 + o] = bo[o] + ((a[0] + a[1]) + (a[2] + a[3]))
                              + ((b4[0] + b4[1]) + (b4[2] + b4[3]));
  }
}

// ------------------------------------------------------------------
// 3) projections via MFMA, zero LDS. 1 wave-task = (proj, b, 32-n tile),
//    K=256 = 16 x mfma_f32_32x32x16_bf16.
//    x-blocks (bid<256): waves = 4 projs {f1,g1,h1,h2} of chunk=bid.
//    y-blocks: 4 waves = 2 chunks x {f2,g2}.
//    Q/K: D = mfma(W, X) -> D[ch][n]; V: D = mfma(X, W) -> D[key][ch].
//    V output instance = ql-2 (h1 -> Vf inst0, h2 -> Vf inst1)
// ------------------------------------------------------------------
__global__ __launch_bounds__(256) void k_proj(
    const float* __restrict__ x, const float* __restrict__ y,
    const uint16_t* __restrict__ wfragb,
    const float* __restrict__ bf1, const float* __restrict__ bg1, const float* __restrict__ bh1,
    const float* __restrict__ bf2, const float* __restrict__ bg2, const float* __restrict__ bh2,
    uint16_t* __restrict__ Qf, uint16_t* __restrict__ Kf, uint16_t* __restrict__ Vf) {
  int bid = blockIdx.x;
  int w = __builtin_amdgcn_readfirstlane(threadIdx.x >> 6);
  int l = threadIdx.x & 63, l31 = l & 31, l5 = l >> 5;

  int q, ql, b, nt, inst;
  const float* src;
  const float* bias;
  bool isf, isV;
  if (bid < 256) {
    ql = w; b = bid >> 7; nt = bid & 127;
    src = x; inst = 0;
    q = (ql == 3) ? 5 : ql;
    isf = (ql == 0); isV = (ql >= 2);
    bias = ql == 0 ? bf1 : ql == 1 ? bg1 : ql == 2 ? bh1 : bh2;
  } else {
    int u = (bid - 256) * 4 + w;      // 512 y-tasks
    int chunk = u >> 1; ql = u & 1;
    b = chunk >> 7; nt = chunk & 127;
    src = y; inst = 1;
    q = 3 + ql;
    isf = (ql == 0); isV = false;
    bias = ql == 0 ? bf2 : bg2;
  }

  // preload 16 weight frags (16B/lane each)
  const u32x4* wp = (const u32x4*)wfragb + (size_t)q * 16 * 64 + l;
  u32x4 wfr[16];
#pragma unroll
  for (int kb = 0; kb < 16; ++kb) wfr[kb] = wp[kb * 64];

  const float* sp = src + (size_t)b * CC * N + (size_t)(l5 * 8) * N + nt * 32 + l31;
  f32x16 acc;
#pragma unroll
  for (int r = 0; r < 16; ++r) acc[r] = 0.f;

  if (isV) {
#pragma unroll
    for (int kb = 0; kb < 16; ++kb) {
      const float* kp = sp + (size_t)kb * 16 * N;
      float xj[8];
#pragma unroll
      for (int j = 0; j < 8; ++j) xj[j] = kp[(size_t)j * N];
      u32x4 bu;
#pragma unroll
      for (int jh = 0; jh < 4; ++jh) bu[jh] = cvtpk_bf16(xj[2 * jh], xj[2 * jh + 1]);
      acc = __builtin_amdgcn_mfma_f32_32x32x16_bf16(
          __builtin_bit_cast(short8, bu), __builtin_bit_cast(short8, wfr[kb]), acc, 0, 0, 0);
    }
  } else {
#pragma unroll
    for (int kb = 0; kb < 16; ++kb) {
      const float* kp = sp + (size_t)kb * 16 * N;
      float xj[8];
#pragma unroll
      for (int j = 0; j < 8; ++j) xj[j] = kp[(size_t)j * N];
      u32x4 bu;
#pragma unroll
      for (int jh = 0; jh < 4; ++jh) bu[jh] = cvtpk_bf16(xj[2 * jh], xj[2 * jh + 1]);
      acc = __builtin_amdgcn_mfma_f32_32x32x16_bf16(
          __builtin_bit_cast(short8, wfr[kb]), __builtin_bit_cast(short8, bu), acc, 0, 0, 0);
    }
  }

  float p[16];
  if (isV) {
    float bv = bias[l31];                      // D[key][ch=l31]: bias per lane
#pragma unroll
    for (int r = 0; r < 16; ++r) p[r] = acc[r] + bv;
  } else {
#pragma unroll
    for (int r = 0; r < 16; ++r) {
      int crow = (r & 3) + 8 * (r >> 2) + 4 * l5;   // D[ch=crow][n=l31]
      float t = acc[r] + bias[crow];
      p[r] = isf ? t * L2E : t;
    }
  }

  u32x4 lo, hi;
  rows_to_frags(p, lo, hi);

  uint16_t* dstb = isV ? Vf : (isf ? Qf : Kf);
  int oinst = isV ? (ql - 2) : inst;               // h1->inst0, h2->inst1
  int b128 = (oinst * 2 + b) * 128 + nt;
  uint32_t* d0 = (uint32_t*)dstb + (size_t)b128 * 512 + l * 4;
  *(u32x4*)d0 = lo;
  *(u32x4*)(d0 + 256) = hi;
}

// ------------------------------------------------------------------
// 4) MFMA flash attention. Block = 512 thr (8 waves) = one 32-query tile
//    of one (instance, batch). Wave w owns keys [w*512, w*512+512).
//    All loads are frag-layout: base + lane*16B, fully coalesced.
// ------------------------------------------------------------------
__global__ __launch_bounds__(512) void k_attn3(const uint16_t* __restrict__ Qf,
                                               const uint16_t* __restrict__ Kf,
                                               const uint16_t* __restrict__ Vf,
                                               float* __restrict__ aot) {
  __shared__ float redAO[8][32][33];
  __shared__ float redL[8][32];
  int bid = blockIdx.x;
  int qt = bid & 127, b = (bid >> 7) & 1, i = bid >> 8;
  int ia = i >> 1, ik = i & 1;
  int tid = threadIdx.x, w = tid >> 6, l = tid & 63, l31 = l & 31, l5 = l >> 5;

  const uint16_t* Qp = Qf + (size_t)((ia * 2 + b) * 128 + qt) * 1024 + l * 8;
  const uint16_t* Kp = Kf + (size_t)((ik * 2 + b) * 128 + w * 16) * 1024 + l * 8;
  const uint16_t* Vp = Vf + (size_t)((ik * 2 + b) * 128 + w * 16) * 1024 + l * 8;

  short8 bq0 = *(const short8*)(Qp);
  short8 bq1 = *(const short8*)(Qp + 512);

  f32x16 zero16, ao;
#pragma unroll
  for (int r = 0; r < 16; ++r) { zero16[r] = 0.f; ao[r] = 0.f; }
  float lacc = 0.f;

  for (int t = 0; t < 16; ++t) {
    const uint16_t* kt = Kp + t * 1024;
    short8 ak0 = *(const short8*)(kt);
    short8 ak1 = *(const short8*)(kt + 512);
    const uint16_t* vt = Vp + t * 1024;
    short8 bv0 = *(const short8*)(vt);
    short8 bv1 = *(const short8*)(vt + 512);

    f32x16 sa = __builtin_amdgcn_mfma_f32_32x32x16_bf16(ak0, bq0, zero16, 0, 0, 0);
    sa = __builtin_amdgcn_mfma_f32_32x32x16_bf16(ak1, bq1, sa, 0, 0, 0);

    float p[16];
#pragma unroll
    for (int r = 0; r < 16; ++r) p[r] = __builtin_amdgcn_exp2f(sa[r]);

    float t0 = 0.f, t1 = 0.f;
#pragma unroll
    for (int r = 0; r < 8; ++r) { t0 += p[2 * r]; t1 += p[2 * r + 1]; }
    lacc += t0 + t1;

    uint32_t wreg[8];
#pragma unroll
    for (int kh = 0; kh < 2; ++kh) {
      int base = kh * 8;
      uint32_t x0 = cvtpk_bf16(p[base + 0], p[base + 1]);
      uint32_t y0 = cvtpk_bf16(p[base + 4], p[base + 5]);
      asm volatile("v_permlane32_swap_b32 %0, %1" : "+v"(x0), "+v"(y0));
      uint32_t x1 = cvtpk_bf16(p[base + 2], p[base + 3]);
      uint32_t y1 = cvtpk_bf16(p[base + 6], p[base + 7]);
      asm volatile("v_permlane32_swap_b32 %0, %1" : "+v"(x1), "+v"(y1));
      wreg[kh * 4 + 0] = x0; wreg[kh * 4 + 1] = x1; wreg[kh * 4 + 2] = y0; wreg[kh * 4 + 3] = y1;
    }
    short8 pa0, pa1;
    {
      u32x4 u0 = {wreg[0], wreg[1], wreg[2], wreg[3]};
      u32x4 u1 = {wreg[4], wreg[5], wreg[6], wreg[7]};
      pa0 = __builtin_bit_cast(short8, u0);
      pa1 = __builtin_bit_cast(short8, u1);
    }
    ao = __builtin_amdgcn_mfma_f32_32x32x16_bf16(pa0, bv0, ao, 0, 0, 0);
    ao = __builtin_amdgcn_mfma_f32_32x32x16_bf16(pa1, bv1, ao, 0, 0, 0);
  }

  // per-wave partials -> LDS
#pragma unroll
  for (int r = 0; r < 16; ++r) {
    int row = (r & 3) + 8 * (r >> 2) + 4 * l5;       // query within tile
    redAO[w][row][l31] = ao[r];
  }
  lacc += __shfl_xor(lacc, 32);
  if (l < 32) redL[w][l31] = lacc;
  __syncthreads();

  // combine + normalize + transposed write (each thread: q=tid&31, 2 channels)
  int q5 = tid & 31, chb = tid >> 5;                 // chb in [0,16)
  float lsum = 0.f;
#pragma unroll
  for (int ww = 0; ww < 8; ++ww) lsum += redL[ww][q5];
  float inv = __builtin_amdgcn_rcpf(lsum);
  float s0 = 0.f, s1 = 0.f;
#pragma unroll
  for (int ww = 0; ww < 8; ++ww) {
    s0 += redAO[ww][q5][chb];
    s1 += redAO[ww][q5][chb + 16];
  }
  int ib = i * 2 + b;
  float* ob = aot + (size_t)ib * CH * N + qt * 32 + q5;
  ob[(size_t)chb * N] = s0 * inv;
  ob[(size_t)(chb + 16) * N] = s1 * inv;
}

// ------------------------------------------------------------------
// 5) epilogue: out[r][b][o][m] = src + Weff * AO_cat + beff
// ------------------------------------------------------------------
__global__ __launch_bounds__(64) void k_epi(const float* __restrict__ x, const float* __restrict__ y,
                                            const float* __restrict__ aot,
                                            const float* __restrict__ weff,
                                            const float* __restrict__ beff,
                                            float* __restrict__ out) {
  int bid = blockIdx.x;
  int mt = bid & 63, og = (bid >> 6) & 15, b = (bid >> 10) & 1, r = bid >> 11;
  int m = mt * 64 + threadIdx.x;
  int o0 = og * 16;
  const float* src = r == 0 ? x : y;
  const float* A0 = aot + (size_t)(r * 4 + b) * CH * N;        // instance (r, ik=0)
  const float* A1 = aot + (size_t)(r * 4 + 2 + b) * CH * N;    // instance (r, ik=1)
  const float* wrow = weff + (size_t)r * 64 * 256;
  float acc[16];
#pragma unroll
  for (int j = 0; j < 16; ++j) acc[j] = 0.f;
#pragma unroll 4
  for (int ch = 0; ch < 32; ++ch) {
    float av = A0[(size_t)ch * N + m];
    const float* wr = wrow + ch * 256 + o0;
#pragma unroll
    for (int j = 0; j < 16; ++j) acc[j] = fmaf(wr[j], av, acc[j]);
  }
#pragma unroll 4
  for (int ch = 0; ch < 32; ++ch) {
    float av = A1[(size_t)ch * N + m];
    const float* wr = wrow + (32 + ch) * 256 + o0;
#pragma unroll
    for (int j = 0; j < 16; ++j) acc[j] = fmaf(wr[j], av, acc[j]);
  }
  float* outr = out + (size_t)r * 2 * CC * N;
#pragma unroll
  for (int j = 0; j < 16; ++j) {
    int o = o0 + j;
    size_t off = ((size_t)b * CC + o) * N + m;
    outr[off] = src[off] + acc[j] + beff[r * CC + o];
  }
}

extern "C" void kernel_launch(void* const* d_in, const int* in_sizes, int n_in,
                              void* d_out, int out_size, void* d_ws, size_t ws_size,
                              hipStream_t stream) {
  const float* x    = (const float*)d_in[0];
  const float* y    = (const float*)d_in[1];
  const float* wf1  = (const float*)d_in[2];
  const float* bf1  = (const float*)d_in[3];
  const float* wg1  = (const float*)d_in[4];
  const float* bg1  = (const float*)d_in[5];
  const float* wh1  = (const float*)d_in[6];
  const float* bh1  = (const float*)d_in[7];
  const float* wf2  = (const float*)d_in[8];
  const float* bf2  = (const float*)d_in[9];
  const float* wg2  = (const float*)d_in[10];
  const float* bg2  = (const float*)d_in[11];
  const float* wh2  = (const float*)d_in[12];
  const float* bh2  = (const float*)d_in[13];
  const float* wv11 = (const float*)d_in[14];
  const float* bv11 = (const float*)d_in[15];
  const float* wv12 = (const float*)d_in[16];
  const float* bv12 = (const float*)d_in[17];
  const float* wv21 = (const float*)d_in[18];
  const float* bv21 = (const float*)d_in[19];
  const float* wv22 = (const float*)d_in[20];
  const float* bv22 = (const float*)d_in[21];
  const float* wo1  = (const float*)d_in[22];
  const float* bo1  = (const float*)d_in[23];
  const float* wo2  = (const float*)d_in[24];
  const float* bo2  = (const float*)d_in[25];

  float* ws   = (float*)d_ws;
  uint16_t* wfragb = (uint16_t*)(ws + OFF_WFRAG);
  float* wot  = ws + OFF_WOT;
  float* weff = ws + OFF_WEFF;
  float* beff = ws + OFF_BEFF;
  uint16_t* Qf = (uint16_t*)(ws + OFF_QF);
  uint16_t* Kf = (uint16_t*)(ws + OFF_KF);
  uint16_t* Vf = (uint16_t*)(ws + OFF_VF);
  float* aot  = ws + OFF_AOT;
  float* out  = (float*)d_out;

  k_prep<<<1216, 256, 0, stream>>>(wf1, wg1, wh1, wf2, wg2, wh2, wo1, wo2, wfragb, wot);
  k_weff<<<130, 256, 0, stream>>>(wot, wv11, wv12, wv21, wv22,
                                  bv11, bv12, bv21, bv22, bo1, bo2, weff, beff);
  k_proj<<<384, 256, 0, stream>>>(x, y, wfragb, bf1, bg1, bh1, bf2, bg2, bh2, Qf, Kf, Vf);
  k_attn3<<<1024, 512, 0, stream>>>(Qf, Kf, Vf, aot);
  k_epi<<<4096, 64, 0, stream>>>(x, y, aot, weff, beff, out);
}